// Round 1
// 1118.974 us; speedup vs baseline: 1.0001x; 1.0001x over previous
//
#include <hip/hip_runtime.h>

#define N_ROWS  524288
#define C_DIM   128
#define M_DIM   256
#define N_TILES (N_ROWS / 16)
#define GRID    512

typedef __bf16 bf16x8 __attribute__((ext_vector_type(8)));
typedef float  f32x4  __attribute__((ext_vector_type(4)));

__device__ __forceinline__ bf16x8 pack8(const float* f) {
    bf16x8 t;
#pragma unroll
    for (int j = 0; j < 8; ++j) t[j] = (__bf16)f[j];   // compiler pairs into v_cvt_pk_bf16_f32 (RNE)
    return t;
}

// Raw barrier with LDS-only drain: keeps register-destined global loads and
// fire-and-forget global stores in flight across the barrier (HK pattern).
// LDS producer->consumer edges are fully ordered by lgkmcnt(0).
#define BARRIER_LGKM() do { \
    asm volatile("s_waitcnt lgkmcnt(0)" ::: "memory"); \
    __builtin_amdgcn_s_barrier(); \
} while (0)

// Fused: xq = tanh(x@W^T + b); att = softmax(xq@key^T); out = att@mem
// Block = 512 threads = 8 waves. Tile = 16 rows. Wave w owns:
//   GEMM1: output cols [16w,16w+16)   -> W frags  wf[4]   (16 VGPR)
//   GEMM2: output cols [32w,32w+32)   -> key frags kf[2][4] (32 VGPR)
//   GEMM3: output cols [16w,16w+16)   -> mem frags mf[8]  (32 VGPR)
// MFMA 16x16x32_bf16 layouts (guide-verified):
//   A[m][k]: m=lane&15, k=(lane>>4)*8+j ; B[k][n]: n=lane&15, same k
//   C/D:     col=lane&15, row=(lane>>4)*4+reg
__global__ __launch_bounds__(512, 2)
void memk(const float* __restrict__ x, const float* __restrict__ W,
          const float* __restrict__ bias_p, const float* __restrict__ key,
          const float* __restrict__ mem, float* __restrict__ out,
          float* __restrict__ att)
{
    __shared__ __attribute__((aligned(16))) __bf16 xq_lds[16][136];   // +8 pad
    __shared__ __attribute__((aligned(16))) __bf16 att_lds[16][264];  // +8 pad
    __shared__ float ps[16][8];

    const int tid  = threadIdx.x;
    const int w    = tid >> 6;      // wave 0..7
    const int lane = tid & 63;
    const int q    = lane >> 4;     // quad 0..3
    const int i    = lane & 15;

    // ---- one-time: weight fragments into registers (L2-resident reads) ----
    bf16x8 wf[4];
#pragma unroll
    for (int ks = 0; ks < 4; ++ks) {
        const float* p = W + (size_t)(w * 16 + i) * C_DIM + ks * 32 + q * 8;
        float f[8];
#pragma unroll
        for (int j = 0; j < 8; ++j) f[j] = p[j];
        wf[ks] = pack8(f);
    }
    bf16x8 kf[2][4];
#pragma unroll
    for (int t = 0; t < 2; ++t)
#pragma unroll
        for (int ks = 0; ks < 4; ++ks) {
            const float* p = key + (size_t)((2 * w + t) * 16 + i) * C_DIM + ks * 32 + q * 8;
            float f[8];
#pragma unroll
            for (int j = 0; j < 8; ++j) f[j] = p[j];
            kf[t][ks] = pack8(f);
        }
    bf16x8 mf[8];
#pragma unroll
    for (int ks = 0; ks < 8; ++ks) {
        float f[8];
#pragma unroll
        for (int j = 0; j < 8; ++j)
            f[j] = mem[(size_t)(ks * 32 + q * 8 + j) * C_DIM + w * 16 + i];
        mf[ks] = pack8(f);
    }
    const float bias = bias_p[w * 16 + i];

    // ---- x prefetch pipeline (A-frag pattern straight from global) ----
    const int xoff = i * C_DIM + q * 8;
    float4 xs[8];
    int tile = blockIdx.x;
    {
        const float* p = x + (size_t)tile * 16 * C_DIM + xoff;
#pragma unroll
        for (int ks = 0; ks < 4; ++ks) {
            xs[2 * ks]     = *(const float4*)(p + ks * 32);
            xs[2 * ks + 1] = *(const float4*)(p + ks * 32 + 4);
        }
    }

    for (; tile < N_TILES; tile += GRID) {
        // convert staged x -> bf16 A frags
        bf16x8 a1[4];
#pragma unroll
        for (int ks = 0; ks < 4; ++ks) {
            float f[8];
            *(float4*)&f[0] = xs[2 * ks];
            *(float4*)&f[4] = xs[2 * ks + 1];
            a1[ks] = pack8(f);
        }
        // prefetch next tile (stays in flight across BOTH barriers now)
        {
            int tn = tile + GRID;
            if (tn >= N_TILES) tn = tile;
            const float* p = x + (size_t)tn * 16 * C_DIM + xoff;
#pragma unroll
            for (int ks = 0; ks < 4; ++ks) {
                xs[2 * ks]     = *(const float4*)(p + ks * 32);
                xs[2 * ks + 1] = *(const float4*)(p + ks * 32 + 4);
            }
        }

        // ---- GEMM1: xq_pre = x @ W^T ----
        f32x4 acc1 = {0.f, 0.f, 0.f, 0.f};
#pragma unroll
        for (int ks = 0; ks < 4; ++ks)
            acc1 = __builtin_amdgcn_mfma_f32_16x16x32_bf16(a1[ks], wf[ks], acc1, 0, 0, 0);

        // tanh + stage xq (bf16) for GEMM2 A-operand
#pragma unroll
        for (int r = 0; r < 4; ++r) {
            float v  = acc1[r] + bias;
            float ex = __expf(2.0f * v);
            float th = 1.0f - 2.0f * __builtin_amdgcn_rcpf(ex + 1.0f);
            xq_lds[q * 4 + r][w * 16 + i] = (__bf16)th;
        }
        BARRIER_LGKM();   // B1 (no vmcnt drain)

        // ---- GEMM2: logits = xq @ key^T (wave's 32 cols) ----
        bf16x8 a2[4];
#pragma unroll
        for (int ks = 0; ks < 4; ++ks)
            a2[ks] = *(const bf16x8*)&xq_lds[i][ks * 32 + q * 8];
        f32x4 acc2[2] = {{0.f,0.f,0.f,0.f}, {0.f,0.f,0.f,0.f}};
#pragma unroll
        for (int t = 0; t < 2; ++t)
#pragma unroll
            for (int ks = 0; ks < 4; ++ks)
                acc2[t] = __builtin_amdgcn_mfma_f32_16x16x32_bf16(a2[ks], kf[t][ks], acc2[t], 0, 0, 0);

        // exp + per-wave partial row sums (reduce 16 lanes within quad)
        float e0[4], e1[4], part[4];
#pragma unroll
        for (int r = 0; r < 4; ++r) {
            e0[r] = __expf(acc2[0][r]);
            e1[r] = __expf(acc2[1][r]);
            part[r] = e0[r] + e1[r];
        }
#pragma unroll
        for (int r = 0; r < 4; ++r) {
            part[r] += __shfl_xor(part[r], 1);
            part[r] += __shfl_xor(part[r], 2);
            part[r] += __shfl_xor(part[r], 4);
            part[r] += __shfl_xor(part[r], 8);
        }
        // stage UNNORMALIZED exp (bf16) for GEMM3; normalization folded in later
#pragma unroll
        for (int r = 0; r < 4; ++r) {
            att_lds[q * 4 + r][(2 * w)     * 16 + i] = (__bf16)e0[r];
            att_lds[q * 4 + r][(2 * w + 1) * 16 + i] = (__bf16)e1[r];
        }
        if (i == 0) {
#pragma unroll
            for (int r = 0; r < 4; ++r) ps[q * 4 + r][w] = part[r];
        }
        BARRIER_LGKM();   // B2 (no vmcnt drain)

        // row sums across the 8 waves
        float inv[4];
#pragma unroll
        for (int r = 0; r < 4; ++r) {
            const float4* p4 = (const float4*)ps[q * 4 + r];
            float4 A = p4[0], B = p4[1];
            float s = ((A.x + A.y) + (A.z + A.w)) + ((B.x + B.y) + (B.z + B.w));
            inv[r] = __builtin_amdgcn_rcpf(s);
        }

        // att output (f32, exact softmax values)
        float* attp = att + (size_t)tile * 16 * M_DIM;
#pragma unroll
        for (int r = 0; r < 4; ++r) {
            attp[(q * 4 + r) * M_DIM + (2 * w)     * 16 + i] = e0[r] * inv[r];
            attp[(q * 4 + r) * M_DIM + (2 * w + 1) * 16 + i] = e1[r] * inv[r];
        }

        // ---- GEMM3: out = (expU @ mem) * inv ----
        f32x4 acc3 = {0.f, 0.f, 0.f, 0.f};
#pragma unroll
        for (int ks = 0; ks < 8; ++ks) {
            bf16x8 a3 = *(const bf16x8*)&att_lds[i][ks * 32 + q * 8];
            acc3 = __builtin_amdgcn_mfma_f32_16x16x32_bf16(a3, mf[ks], acc3, 0, 0, 0);
        }
        float* outp = out + (size_t)tile * 16 * C_DIM;
#pragma unroll
        for (int r = 0; r < 4; ++r)
            outp[(q * 4 + r) * C_DIM + w * 16 + i] = acc3[r] * inv[r];
    }
}

extern "C" void kernel_launch(void* const* d_in, const int* in_sizes, int n_in,
                              void* d_out, int out_size, void* d_ws, size_t ws_size,
                              hipStream_t stream) {
    const float* x    = (const float*)d_in[0];
    const float* W    = (const float*)d_in[1];
    const float* b    = (const float*)d_in[2];
    const float* key  = (const float*)d_in[3];
    const float* mem  = (const float*)d_in[4];
    float* out = (float*)d_out;
    float* att = out + (size_t)N_ROWS * C_DIM;
    hipLaunchKernelGGL(memk, dim3(GRID), dim3(512), 0, stream,
                       x, W, b, key, mem, out, att);
}